// Round 26
// baseline (705.931 us; speedup 1.0000x reference)
//
#include <hip/hip_runtime.h>
#include <math.h>

// Residual VQ: x (262144,128) fp32, codebooks (3,256,128) fp32.
// Output: [indices as float (262144*3)] ++ [quantized (262144*128)].
//
// ARITHMETIC CONTRACT (absmax=0 — do not change):
//   M_k  = OpenBLAS sgemm K-loop: sequential FMA chain j=0..127, acc init 0
//   A    = np.sum(r*r): pairwise_sum 8-accumulator scheme, products rounded
//          separately (fmaf(x,x,0) = single-rounded product, blocks fusion)
//   d2_k = (A - 2.0f*M_k) + B_k ; argmin strict < ascending k == first-min
//          (per-lane v-ascending strict-<, then (val,idx) shuffle-reduce
//           with tie -> smaller idx: identical semantics)
//   residual: r1 = x - q0, r2 = r1 - q1 — in-place global scratch, ref order
//   quantized = (q0 + q1) + q2 elementwise fp32, ref order
//
// ROUND 30 CHANGE: r28/r29 faulted at runtime. Root cause (vs r26 which
// worked: its asm issued AND waited inside one block — no SMEM in flight
// across C++): the final loop iteration's clamped SLOAD_LO(pn=31) was a
// DUMMY — its rv0..7 outputs are never read, so the allocator reuses those
// physical SGPRs right after the block while 8 s_loads are still in flight;
// the late writes clobber live registers (argmin/output addressing) ->
// wild addresses -> abort. Early-clobber can't fix a lifetime bug. Fix:
// REMOVE ALL DUMMY ISSUES structurally — main loop pp=0..14 (phases 0..29,
// pn=pe+2 always consumed), epilogue finishes phases 30/31 and ends with a
// PURE WAIT block (ties rv8..15, zero issues): nothing in flight at loop
// exit. Design otherwise r27: [wait][issue next][compute cur] half-batch
// SGPR ping-pong (2x32 SGPRs) + q VGPR ping-pong; per-phase lgkm drain
// (~250cyc K$-miss) hidden under the other half's 256cyc of FMAs.
// PRE-COMMIT: fault or regression here -> revert to r26 (702us), declare.

constexpr int kItems = 262144;
constexpr int kDim   = 128;
constexpr int kNcb   = 3;
constexpr int kK     = 256;
constexpr int kBlock = 256;
constexpr int kBatch = 16;        // items per wave (wave-private batch)
constexpr int NPH    = 32;        // phases of 4 dims

typedef float sf4 __attribute__((ext_vector_type(4)));

__device__ __forceinline__ float sq_rn(float x) {
    return __builtin_fmaf(x, x, 0.0f);
}

// numpy pairwise_sum, n=128 (for the B-table)
template <typename F>
__device__ __forceinline__ float np_pairwise128(F term) {
    float r0 = term(0), r1 = term(1), r2 = term(2), r3 = term(3),
          r4 = term(4), r5 = term(5), r6 = term(6), r7 = term(7);
    #pragma unroll
    for (int i = 8; i < 128; i += 8) {
        r0 = r0 + term(i + 0); r1 = r1 + term(i + 1);
        r2 = r2 + term(i + 2); r3 = r3 + term(i + 3);
        r4 = r4 + term(i + 4); r5 = r5 + term(i + 5);
        r6 = r6 + term(i + 6); r7 = r7 + term(i + 7);
    }
    return ((r0 + r1) + (r2 + r3)) + ((r4 + r5) + (r6 + r7));
}

// ---------- pre-kernel: Bt (768 floats) + phase-major codebook cbT2:
// cbT2[(((c*32+p)*4 + v)*64 + l)*4 + d] = cb[(c*256 + 64v+l)*128 + 4p+d]
__global__ void rvq_prep(const float* __restrict__ cb,
                         float* __restrict__ Bt,
                         float* __restrict__ cbT2)
{
    const int tid = blockIdx.x * 256 + threadIdx.x;   // 384*256 = 98304
    const int d = tid & 3;
    const int l = (tid >> 2) & 63;
    const int v = (tid >> 8) & 3;
    const int p = (tid >> 10) & 31;
    const int c = tid >> 15;
    cbT2[tid] = cb[((size_t)c * kK + 64 * v + l) * kDim + (4 * p + d)];
    if (tid < kNcb * kK) {
        const float* row = cb + (size_t)tid * kDim;
        Bt[tid] = np_pairwise128([&](int jj) { return sq_rn(row[jj]); });
    }
}

#define X16(X) X(0) X(1) X(2) X(3) X(4) X(5) X(6) X(7) \
  X(8) X(9) X(10) X(11) X(12) X(13) X(14) X(15)

#define MDECL(i) float m##i##_0 = 0.f, m##i##_1 = 0.f, \
                       m##i##_2 = 0.f, m##i##_3 = 0.f;

// 16 FMAs for item i: RV (SGPR quad) x Q tile (VGPR). Per-acc chain:
// d ascending within phase, phases ascending -> j=0..127 sequential.
// Every Q paste parenthesized — (Q##2).y — else "2.y" lexes as one
// pp-number and pasting forms an invalid token (r27 lesson).
#define FMAS(i, RV, Q) \
    m##i##_0 = __builtin_fmaf(RV.x, (Q##0).x, m##i##_0); \
    m##i##_0 = __builtin_fmaf(RV.y, (Q##0).y, m##i##_0); \
    m##i##_0 = __builtin_fmaf(RV.z, (Q##0).z, m##i##_0); \
    m##i##_0 = __builtin_fmaf(RV.w, (Q##0).w, m##i##_0); \
    m##i##_1 = __builtin_fmaf(RV.x, (Q##1).x, m##i##_1); \
    m##i##_1 = __builtin_fmaf(RV.y, (Q##1).y, m##i##_1); \
    m##i##_1 = __builtin_fmaf(RV.z, (Q##1).z, m##i##_1); \
    m##i##_1 = __builtin_fmaf(RV.w, (Q##1).w, m##i##_1); \
    m##i##_2 = __builtin_fmaf(RV.x, (Q##2).x, m##i##_2); \
    m##i##_2 = __builtin_fmaf(RV.y, (Q##2).y, m##i##_2); \
    m##i##_2 = __builtin_fmaf(RV.z, (Q##2).z, m##i##_2); \
    m##i##_2 = __builtin_fmaf(RV.w, (Q##2).w, m##i##_2); \
    m##i##_3 = __builtin_fmaf(RV.x, (Q##3).x, m##i##_3); \
    m##i##_3 = __builtin_fmaf(RV.y, (Q##3).y, m##i##_3); \
    m##i##_3 = __builtin_fmaf(RV.z, (Q##3).z, m##i##_3); \
    m##i##_3 = __builtin_fmaf(RV.w, (Q##3).w, m##i##_3);

#define FHALF_LO(Q) FMAS(0,rv0,Q) FMAS(1,rv1,Q) FMAS(2,rv2,Q) FMAS(3,rv3,Q) \
                    FMAS(4,rv4,Q) FMAS(5,rv5,Q) FMAS(6,rv6,Q) FMAS(7,rv7,Q)
#define FHALF_HI(Q) FMAS(8,rv8,Q) FMAS(9,rv9,Q) FMAS(10,rv10,Q) FMAS(11,rv11,Q) \
                    FMAS(12,rv12,Q) FMAS(13,rv13,Q) FMAS(14,rv14,Q) FMAS(15,rv15,Q)

#define QDECL(P) float4 P##0, P##1, P##2, P##3;
#define QLOAD(P, PH) { \
    const float4* cbq_ = (const float4*)(cbTc + ((size_t)(PH) * 4) * 256) + lane; \
    P##0 = cbq_[0]; P##1 = cbq_[64]; P##2 = cbq_[128]; P##3 = cbq_[192]; }

// prologue: drain pending SMEM, issue H1(0)
#define SLOAD_PRO(BASE) asm volatile( \
    "s_waitcnt lgkmcnt(0)\n\t" \
    "s_load_dwordx4 %[r0], %[b], 0x0\n\t" \
    "s_load_dwordx4 %[r1], %[b], 0x200\n\t" \
    "s_load_dwordx4 %[r2], %[b], 0x400\n\t" \
    "s_load_dwordx4 %[r3], %[b], 0x600\n\t" \
    "s_load_dwordx4 %[r4], %[b], 0x800\n\t" \
    "s_load_dwordx4 %[r5], %[b], 0xa00\n\t" \
    "s_load_dwordx4 %[r6], %[b], 0xc00\n\t" \
    "s_load_dwordx4 %[r7], %[b], 0xe00" \
    : [r0]"=&s"(rv0), [r1]"=&s"(rv1), [r2]"=&s"(rv2), [r3]"=&s"(rv3), \
      [r4]"=&s"(rv4), [r5]"=&s"(rv5), [r6]"=&s"(rv6), [r7]"=&s"(rv7) \
    : [b]"s"(BASE) : "memory")

// wait (H1 arrives) + issue H2 = items 8..15; ties rv0..7 so the following
// FHALF_LO cannot hoist above the wait
#define SLOAD_HI(BASE) asm volatile( \
    "s_waitcnt lgkmcnt(0)\n\t" \
    "s_load_dwordx4 %[r8],  %[b], 0x1000\n\t" \
    "s_load_dwordx4 %[r9],  %[b], 0x1200\n\t" \
    "s_load_dwordx4 %[r10], %[b], 0x1400\n\t" \
    "s_load_dwordx4 %[r11], %[b], 0x1600\n\t" \
    "s_load_dwordx4 %[r12], %[b], 0x1800\n\t" \
    "s_load_dwordx4 %[r13], %[b], 0x1a00\n\t" \
    "s_load_dwordx4 %[r14], %[b], 0x1c00\n\t" \
    "s_load_dwordx4 %[r15], %[b], 0x1e00" \
    : [r8]"=&s"(rv8),  [r9]"=&s"(rv9),  [r10]"=&s"(rv10), [r11]"=&s"(rv11), \
      [r12]"=&s"(rv12), [r13]"=&s"(rv13), [r14]"=&s"(rv14), [r15]"=&s"(rv15), \
      [t0]"+s"(rv0), [t1]"+s"(rv1), [t2]"+s"(rv2), [t3]"+s"(rv3), \
      [t4]"+s"(rv4), [t5]"+s"(rv5), [t6]"+s"(rv6), [t7]"+s"(rv7) \
    : [b]"s"(BASE) : "memory")

// wait (H2 arrives) + issue H1 = items 0..7; ties rv8..15
#define SLOAD_LO(BASE) asm volatile( \
    "s_waitcnt lgkmcnt(0)\n\t" \
    "s_load_dwordx4 %[r0], %[b], 0x0\n\t" \
    "s_load_dwordx4 %[r1], %[b], 0x200\n\t" \
    "s_load_dwordx4 %[r2], %[b], 0x400\n\t" \
    "s_load_dwordx4 %[r3], %[b], 0x600\n\t" \
    "s_load_dwordx4 %[r4], %[b], 0x800\n\t" \
    "s_load_dwordx4 %[r5], %[b], 0xa00\n\t" \
    "s_load_dwordx4 %[r6], %[b], 0xc00\n\t" \
    "s_load_dwordx4 %[r7], %[b], 0xe00" \
    : [r0]"=&s"(rv0), [r1]"=&s"(rv1), [r2]"=&s"(rv2), [r3]"=&s"(rv3), \
      [r4]"=&s"(rv4), [r5]"=&s"(rv5), [r6]"=&s"(rv6), [r7]"=&s"(rv7), \
      [t8]"+s"(rv8),  [t9]"+s"(rv9),  [t10]"+s"(rv10), [t11]"+s"(rv11), \
      [t12]"+s"(rv12), [t13]"+s"(rv13), [t14]"+s"(rv14), [t15]"+s"(rv15) \
    : [b]"s"(BASE) : "memory")

// pure wait, ZERO issues: drains the last H2 loads; ties rv8..15. After
// this block nothing is in flight — no dead-output clobber window.
#define SWAIT_HI() asm volatile( \
    "s_waitcnt lgkmcnt(0)" \
    : [t8]"+s"(rv8),  [t9]"+s"(rv9),  [t10]"+s"(rv10), [t11]"+s"(rv11), \
      [t12]"+s"(rv12), [t13]"+s"(rv13), [t14]"+s"(rv14), [t15]"+s"(rv15) \
    :: "memory")

// d2 + argmin for item i (strict <, v ascending, then butterfly; tie ->
// smaller idx == numpy first-min over all 256 entries)
#define ARGMIN(i) { \
    const float Ai = __shfl(Areg, (i)); \
    float bv = __builtin_fmaf(-2.0f, m##i##_0, Ai) + B0; \
    int   bx = lane; \
    float dd = __builtin_fmaf(-2.0f, m##i##_1, Ai) + B1; \
    if (dd < bv) { bv = dd; bx = 64 + lane; } \
    dd = __builtin_fmaf(-2.0f, m##i##_2, Ai) + B2; \
    if (dd < bv) { bv = dd; bx = 128 + lane; } \
    dd = __builtin_fmaf(-2.0f, m##i##_3, Ai) + B3; \
    if (dd < bv) { bv = dd; bx = 192 + lane; } \
    _Pragma("unroll") \
    for (int off = 32; off; off >>= 1) { \
        const float ov = __shfl_xor(bv, off); \
        const int   ox = __shfl_xor(bx, off); \
        const bool take = (ov < bv) || (ov == bv && ox < bx); \
        bv = take ? ov : bv; bx = take ? ox : bx; \
    } \
    if (c == 0)      sel0 = (lane == (i)) ? bx : sel0; \
    else if (c == 1) sel1 = (lane == (i)) ? bx : sel1; \
    else             sel2 = (lane == (i)) ? bx : sel2; }

__global__ __launch_bounds__(kBlock, 2) void rvq_kernel(
    const float* __restrict__ x,
    const float* __restrict__ cb,
    const float* __restrict__ Bt,
    const float* __restrict__ cbT2,
    float* __restrict__ out)
{
    const int t = threadIdx.x;
    const int lane = t & 63;
    const int wid = blockIdx.x * (kBlock / 64) + (t >> 6);
    const size_t ibase = (size_t)wid * kBatch;

    float* out_idx = out;                             // (items, 3) as float
    float* out_q   = out + (size_t)kItems * kNcb;     // (items, 128)

    const float* xb = x + ibase * kDim;               // batch x rows
    float*       qb = out_q + ibase * kDim;           // batch scratch rows

    int sel0 = 0, sel1 = 0, sel2 = 0;                 // lane i: item i's sel

    #pragma unroll 1
    for (int c = 0; c < kNcb; ++c) {
        const float* rb_ = (c == 0) ? xb : (const float*)qb;
        const float* cbTc = cbT2 + (size_t)c * 32768;  // 32 phases*4v*64l*4d

        // uniform SGPR base (readfirstlane-hoist: value IS wave-uniform)
        const uint64_t rbu = (uint64_t)(const void*)rb_;
        const uint32_t blo = __builtin_amdgcn_readfirstlane((uint32_t)rbu);
        const uint32_t bhi = __builtin_amdgcn_readfirstlane((uint32_t)(rbu >> 32));
        const uint64_t sbase = ((uint64_t)bhi << 32) | (uint64_t)blo;

        // rv SGPR sets (H1 = items 0..7, H2 = items 8..15)
        sf4 rv0, rv1, rv2, rv3, rv4, rv5, rv6, rv7,
            rv8, rv9, rv10, rv11, rv12, rv13, rv14, rv15;

        // prologue: (nothing in flight at this point) issue H1(0); q tile
        // set A for phase 0. Latency of both covered by the A-pass below.
        SLOAD_PRO(sbase);
        QDECL(qa_) QDECL(qb_)
        QLOAD(qa_, 0)

        // ---- A: lane i computes item i's np.sum(r*r), 8-stripe pairwise
        float Areg = 0.0f;
        if (lane < kBatch) {
            const float4* rr = (const float4*)(rb_ + (size_t)lane * kDim);
            float4 ra = rr[0], rb2v = rr[1];
            float a0 = sq_rn(ra.x),   a1 = sq_rn(ra.y),
                  a2 = sq_rn(ra.z),   a3 = sq_rn(ra.w),
                  a4 = sq_rn(rb2v.x), a5 = sq_rn(rb2v.y),
                  a6 = sq_rn(rb2v.z), a7 = sq_rn(rb2v.w);
            #pragma unroll
            for (int g = 1; g < 16; ++g) {
                ra = rr[2 * g]; rb2v = rr[2 * g + 1];
                a0 = a0 + sq_rn(ra.x);   a1 = a1 + sq_rn(ra.y);
                a2 = a2 + sq_rn(ra.z);   a3 = a3 + sq_rn(ra.w);
                a4 = a4 + sq_rn(rb2v.x); a5 = a5 + sq_rn(rb2v.y);
                a6 = a6 + sq_rn(rb2v.z); a7 = a7 + sq_rn(rb2v.w);
            }
            Areg = ((a0 + a1) + (a2 + a3)) + ((a4 + a5) + (a6 + a7));
        }

        // ---- M: 64 accs; rv half-phase ping-pong (SGPR), q ping-pong
        // (VGPR). Main loop phases 0..29; every issued load is consumed.
        X16(MDECL)
        #pragma unroll 1
        for (int pp = 0; pp < NPH / 2 - 1; ++pp) {       // pp = 0..14
            const int pe = 2 * pp;                       // even phase
            const int po = 2 * pp + 1;                   // odd phase
            const int pn = pe + 2;                       // next even (<=30)

            // even phase pe (q = qa_)
            SLOAD_HI(sbase + (uint64_t)(16 * pe));   // wait H1(pe); issue H2(pe)
            QLOAD(qb_, po)                           // q prefetch for odd
            FHALF_LO(qa_)
            SLOAD_LO(sbase + (uint64_t)(16 * po));   // wait H2(pe); issue H1(po)
            FHALF_HI(qa_)

            // odd phase po (q = qb_)
            SLOAD_HI(sbase + (uint64_t)(16 * po));   // wait H1(po); issue H2(po)
            QLOAD(qa_, pn)                           // q prefetch for next even
            FHALF_LO(qb_)
            SLOAD_LO(sbase + (uint64_t)(16 * pn));   // wait H2(po); issue H1(pn)
            FHALF_HI(qb_)
        }

        // ---- epilogue: phases 30 (qa_) and 31 (qb_), NO dummy issues;
        // ends with a pure wait -> zero loads in flight at exit
        SLOAD_HI(sbase + (uint64_t)(16 * 30));       // wait H1(30); issue H2(30)
        QLOAD(qb_, 31)
        FHALF_LO(qa_)
        SLOAD_LO(sbase + (uint64_t)(16 * 31));       // wait H2(30); issue H1(31)
        FHALF_HI(qa_)
        SLOAD_HI(sbase + (uint64_t)(16 * 31));       // wait H1(31); issue H2(31)
        FHALF_LO(qb_)
        SWAIT_HI();                                  // wait H2(31); no issue
        FHALF_HI(qb_)

        // ---- argmin (B per-lane, coalesced)
        const float* Btc = Bt + c * kK;
        const float B0 = Btc[lane],       B1 = Btc[64 + lane];
        const float B2 = Btc[128 + lane], B3 = Btc[192 + lane];
        X16(ARGMIN)

        // ---- residual update into wave-private scratch rows (vector)
        if (c < 2) {
            #pragma unroll 1
            for (int i = 0; i < kBatch; ++i) {
                const int s = __shfl((c == 0) ? sel0 : sel1, i);
                const float* cwrow = cb + ((size_t)c * kK + s) * kDim;
                const float2 w = *(const float2*)(cwrow + 2 * lane);
                float* dr = qb + (size_t)i * kDim;
                const float* sr = (c == 0) ? (xb + (size_t)i * kDim)
                                           : (const float*)dr;
                float2 rv = *(const float2*)(sr + 2 * lane);
                rv.x = rv.x - w.x;             // one rounding each, ref order
                rv.y = rv.y - w.y;
                *(float2*)(dr + 2 * lane) = rv;
            }
            // drain vector writes, then invalidate the scalar K$ so the
            // next codebook's s_loads observe the fresh residuals
            asm volatile("s_waitcnt vmcnt(0)" ::: "memory");
            __builtin_amdgcn_s_dcache_inv();
        }
    }

    // ---- outputs: quantized (overwrites scratch; all r2 reads done) + idx
    #pragma unroll 1
    for (int i = 0; i < kBatch; ++i) {
        const int s0 = __shfl(sel0, i);
        const int s1 = __shfl(sel1, i);
        const int s2 = __shfl(sel2, i);
        const float2 u = *(const float2*)(cb + ((size_t)0 * kK + s0) * kDim + 2 * lane);
        const float2 v = *(const float2*)(cb + ((size_t)1 * kK + s1) * kDim + 2 * lane);
        const float2 w = *(const float2*)(cb + ((size_t)2 * kK + s2) * kDim + 2 * lane);
        float2 o;
        o.x = (u.x + v.x) + w.x;               // ((0+q0)+q1)+q2, ref order
        o.y = (u.y + v.y) + w.y;
        *(float2*)(qb + (size_t)i * kDim + 2 * lane) = o;
        if (lane == 0) {
            out_idx[(ibase + i) * kNcb + 0] = (float)s0;
            out_idx[(ibase + i) * kNcb + 1] = (float)s1;
            out_idx[(ibase + i) * kNcb + 2] = (float)s2;
        }
    }
}

extern "C" void kernel_launch(void* const* d_in, const int* in_sizes, int n_in,
                              void* d_out, int out_size, void* d_ws, size_t ws_size,
                              hipStream_t stream) {
    const float* x  = (const float*)d_in[0];
    const float* cb = (const float*)d_in[1];
    float* out = (float*)d_out;
    float* Bt  = (float*)d_ws;                 // 768 floats
    float* cbT2 = (float*)d_ws + 1024;         // 98304 floats (384 KB)
    rvq_prep<<<384, 256, 0, stream>>>(cb, Bt, cbT2);
    // 16384 waves (one 16-item batch each) = 4096 blocks x 4 waves
    rvq_kernel<<<kItems / (kBatch * 4), kBlock, 0, stream>>>(x, cb, Bt, cbT2, out);
}